// Round 12
// baseline (336.943 us; speedup 1.0000x reference)
//
#include <hip/hip_runtime.h>
#include <hip/hip_bf16.h>
#include <math.h>

// ---------------------------------------------------------------------------
// 2-layer GAT on MI355X.
// R12: (a) agg kernels prefetch first-16 edge h-rows BEFORE the p-phase LDS
// barrier (R11 serialized the two independent latency chains); (b) conv1
// attention scores stored fp16 (halves p-phase scattered line traffic).
// Rest = R11: cnt-bounded p-phase, fused {bhist||gemm1} {bscan||attn1},
// bucket-sort CSR, MFMA GEMMs.
// ---------------------------------------------------------------------------

typedef __attribute__((ext_vector_type(8))) short short8;
typedef __attribute__((ext_vector_type(4))) float f32x4;

__device__ __forceinline__ float bflo(uint u) { return __uint_as_float(u << 16); }
__device__ __forceinline__ float bfhi(uint u) { return __uint_as_float(u & 0xffff0000u); }
__device__ __forceinline__ float bf1(ushort v) { return __uint_as_float(((uint)v) << 16); }
__device__ __forceinline__ ushort f2bf(float f) {  // RNE f32->bf16
    uint u = __float_as_uint(f);
    u += 0x7fff + ((u >> 16) & 1);
    return (ushort)(u >> 16);
}
#define LOG2E 1.44269504088896f
#define CSR_CAP 4096

// ---------------- K_A: fused bucket-histogram + conv1 GEMM -----------------
__global__ __launch_bounds__(256) void k_gemm1_bhist(
    const float* __restrict__ X, const float* __restrict__ W,
    ushort* __restrict__ Y, int n,
    const int* __restrict__ dst, int e, int* __restrict__ bcount, int nbh) {
    __shared__ union {
        struct { ushort As[128][136]; ushort Ws[128][136]; } g;
        int h[1024];
    } sm;
    const int t = threadIdx.x;
    if ((int)blockIdx.x < nbh) {
        for (int i = t; i < 1024; i += 256) sm.h[i] = 0;
        __syncthreads();
        int c0 = blockIdx.x * 8192, c1 = min(c0 + 8192, e);
        for (int i = c0 + t; i < c1; i += 256) atomicAdd(&sm.h[dst[i] >> 7], 1);
        __syncthreads();
        for (int i = t; i < 1024; i += 256)
            if (sm.h[i]) atomicAdd(&bcount[i], sm.h[i]);
        return;
    }
    const int row0 = (blockIdx.x - nbh) * 128;
#pragma unroll
    for (int q = 0; q < 16; q++) {
        int idx = t + q * 256;
        int r = idx >> 5, c4 = (idx & 31) * 4;
        float4 xv = make_float4(0.f, 0.f, 0.f, 0.f);
        if (row0 + r < n) xv = *reinterpret_cast<const float4*>(&X[(size_t)(row0 + r) * 128 + c4]);
        ushort4 w4 = make_ushort4(f2bf(xv.x), f2bf(xv.y), f2bf(xv.z), f2bf(xv.w));
        *reinterpret_cast<ushort4*>(&sm.g.As[r][c4]) = w4;
    }
    for (int i = t; i < 128 * 128; i += 256) {
        int k = i >> 7, nc = i & 127;
        sm.g.Ws[nc][k] = f2bf(W[i]);
    }
    __syncthreads();
    const int w = t >> 6, l = t & 63;
    const int lr = l & 15;
    const int lk = (l >> 4) * 8;
    f32x4 acc[2][8];
#pragma unroll
    for (int m = 0; m < 2; m++)
#pragma unroll
        for (int nb = 0; nb < 8; nb++) acc[m][nb] = (f32x4){0.f, 0.f, 0.f, 0.f};
#pragma unroll
    for (int kc = 0; kc < 128; kc += 32) {
        short8 a0 = *reinterpret_cast<const short8*>(&sm.g.As[w * 32 + lr][kc + lk]);
        short8 a1 = *reinterpret_cast<const short8*>(&sm.g.As[w * 32 + 16 + lr][kc + lk]);
#pragma unroll
        for (int nb = 0; nb < 8; nb++) {
            short8 bf = *reinterpret_cast<const short8*>(&sm.g.Ws[nb * 16 + lr][kc + lk]);
            acc[0][nb] = __builtin_amdgcn_mfma_f32_16x16x32_bf16(a0, bf, acc[0][nb], 0, 0, 0);
            acc[1][nb] = __builtin_amdgcn_mfma_f32_16x16x32_bf16(a1, bf, acc[1][nb], 0, 0, 0);
        }
    }
#pragma unroll
    for (int m = 0; m < 2; m++)
#pragma unroll
        for (int j = 0; j < 4; j++) {
            int r = row0 + w * 32 + m * 16 + (l >> 4) * 4 + j;
            if (r < n) {
#pragma unroll
                for (int nb = 0; nb < 8; nb++)
                    Y[(size_t)r * 128 + nb * 16 + lr] = f2bf(acc[m][nb][j]);
            }
        }
}

// ---------------- K_B: fused bucket-scan + conv1 attention (fp16 out) ------
__global__ __launch_bounds__(256) void k_bscan_attn1(
    const int* __restrict__ bcount, int nb, int n,
    int* __restrict__ ebase, int* __restrict__ ecur, int* __restrict__ cbase,
    const uint* __restrict__ hu, const float* __restrict__ a_src,
    const float* __restrict__ a_dst, _Float16* __restrict__ asrc,
    _Float16* __restrict__ adst) {
    __shared__ int ae[1024], be[1024], ac[1024], bc[1024];
    int t = threadIdx.x;
    if (blockIdx.x == 0) {
        for (int i = t; i < 1024; i += 256) {
            int v = 0, nn = 0;
            if (i < nb) {
                v = bcount[i];
                nn = min(128, n - (i << 7));
            }
            ae[i] = v;
            ac[i] = v + nn;
        }
        __syncthreads();
        int* pa = ae; int* qa = be; int* pc = ac; int* qc = bc;
        for (int off = 1; off < 1024; off <<= 1) {
            for (int i = t; i < 1024; i += 256) {
                int va = pa[i], vc = pc[i];
                if (i >= off) { va += pa[i - off]; vc += pc[i - off]; }
                qa[i] = va; qc[i] = vc;
            }
            __syncthreads();
            int* tm = pa; pa = qa; qa = tm;
            tm = pc; pc = qc; qc = tm;
        }
        for (int i = t; i < 1024; i += 256) {
            if (i < nb) {
                int ea = (i == 0) ? 0 : pa[i - 1];
                int ca = (i == 0) ? 0 : pc[i - 1];
                ebase[i] = ea; ecur[i] = ea; cbase[i] = ca;
            }
        }
        return;
    }
    int tt = (blockIdx.x - 1) * 256 + t;
    if (tt >= n * 8) return;
    int node = tt >> 3, hd = tt & 7;
    const uint* hp = hu + (size_t)node * 64 + hd * 8;
    float s1 = 0.f, s2 = 0.f;
#pragma unroll
    for (int q = 0; q < 8; q++) {
        uint u = hp[q];
        float v0 = bflo(u), v1 = bfhi(u);
        s1 = fmaf(v0, a_src[hd * 16 + 2 * q], s1);
        s1 = fmaf(v1, a_src[hd * 16 + 2 * q + 1], s1);
        s2 = fmaf(v0, a_dst[hd * 16 + 2 * q], s2);
        s2 = fmaf(v1, a_dst[hd * 16 + 2 * q + 1], s2);
    }
    asrc[tt] = (_Float16)(s1 * LOG2E);
    adst[tt] = (_Float16)(s2 * LOG2E);
}

// ---------------- partition + build (unchanged) ----------------------------
__global__ __launch_bounds__(512) void k_part(const int* __restrict__ src,
                                              const int* __restrict__ dst, int e,
                                              int* __restrict__ ecur, int* __restrict__ ebuf) {
    __shared__ int h[1024];
    __shared__ int base[1024];
    int t = threadIdx.x;
    int c0 = blockIdx.x * 8192, c1 = min(c0 + 8192, e);
    for (int i = t; i < 1024; i += 512) h[i] = 0;
    __syncthreads();
    for (int i = c0 + t; i < c1; i += 512) atomicAdd(&h[dst[i] >> 7], 1);
    __syncthreads();
    for (int i = t; i < 1024; i += 512) {
        int c = h[i];
        base[i] = c ? atomicAdd(&ecur[i], c) : 0;
        h[i] = 0;
    }
    __syncthreads();
    for (int i = c0 + t; i < c1; i += 512) {
        int d = dst[i], b = d >> 7;
        int r = atomicAdd(&h[b], 1);
        ebuf[base[b] + r] = (src[i] << 7) | (d & 127);
    }
}

__global__ __launch_bounds__(256) void k_build(const int* __restrict__ ebuf,
                                               const int* __restrict__ bcount,
                                               const int* __restrict__ ebase,
                                               const int* __restrict__ cbase,
                                               int* __restrict__ rowptr,
                                               int* __restrict__ csr, int n, int nb) {
    __shared__ int cnt[128];
    __shared__ int sc[128], sc2[128];
    __shared__ int csr_l[CSR_CAP];
    int b = blockIdx.x, t = threadIdx.x;
    int n0 = b << 7;
    int nn = min(128, n - n0);
    int ec = bcount[b], eb = ebase[b], cb = cbase[b];
    if (t < 128) cnt[t] = 0;
    __syncthreads();
    for (int i = t; i < ec; i += 256) atomicAdd(&cnt[ebuf[eb + i] & 127], 1);
    __syncthreads();
    if (t < 128) sc[t] = (t < nn) ? cnt[t] + 1 : 0;
    __syncthreads();
    int* p = sc; int* q = sc2;
    for (int off = 1; off < 128; off <<= 1) {
        if (t < 128) {
            int v = p[t];
            if (t >= off) v += p[t - off];
            q[t] = v;
        }
        __syncthreads();
        int* tm = p; p = q; q = tm;
    }
    int total = p[127];
    if (total <= CSR_CAP) {
        if (t < nn) {
            int off = (t == 0) ? 0 : p[t - 1];
            rowptr[n0 + t] = cb + off;
            csr_l[off] = n0 + t;
            cnt[t] = off + 1;
        }
        __syncthreads();
        for (int i = t; i < ec; i += 256) {
            int v = ebuf[eb + i];
            int s = atomicAdd(&cnt[v & 127], 1);
            csr_l[s] = v >> 7;
        }
        __syncthreads();
        for (int i = t; i < total; i += 256) csr[cb + i] = csr_l[i];
    } else {
        if (t < nn) {
            int off = (t == 0) ? 0 : p[t - 1];
            rowptr[n0 + t] = cb + off;
            csr[cb + off] = n0 + t;
            cnt[t] = off + 1;
        }
        __syncthreads();
        for (int i = t; i < ec; i += 256) {
            int v = ebuf[eb + i];
            int s = atomicAdd(&cnt[v & 127], 1);
            csr[cb + s] = v >> 7;
        }
    }
    if (b == nb - 1 && t == 0) rowptr[n] = cb + total;
}

// ---------------- conv2 GEMM + attn2 (unchanged) ---------------------------
__global__ __launch_bounds__(256) void k_gemm2(const ushort* __restrict__ X,
                                               const float* __restrict__ W,
                                               ushort* __restrict__ Y, int n) {
    __shared__ ushort As[128][136];
    __shared__ ushort Ws[64][136];
    const int t = threadIdx.x;
    const int row0 = blockIdx.x * 128;
#pragma unroll
    for (int q = 0; q < 8; q++) {
        int idx = t + q * 256;
        int r = idx >> 4, c8 = (idx & 15) * 8;
        uint4 v = make_uint4(0u, 0u, 0u, 0u);
        if (row0 + r < n) v = *reinterpret_cast<const uint4*>(&X[(size_t)(row0 + r) * 128 + c8]);
        *reinterpret_cast<uint4*>(&As[r][c8]) = v;
    }
    for (int i = t; i < 128 * 64; i += 256) {
        int k = i >> 6, nc = i & 63;
        Ws[nc][k] = f2bf(W[i]);
    }
    __syncthreads();
    const int w = t >> 6, l = t & 63;
    const int lr = l & 15;
    const int lk = (l >> 4) * 8;
    f32x4 acc[2][4];
#pragma unroll
    for (int m = 0; m < 2; m++)
#pragma unroll
        for (int nb = 0; nb < 4; nb++) acc[m][nb] = (f32x4){0.f, 0.f, 0.f, 0.f};
#pragma unroll
    for (int kc = 0; kc < 128; kc += 32) {
        short8 a0 = *reinterpret_cast<const short8*>(&As[w * 32 + lr][kc + lk]);
        short8 a1 = *reinterpret_cast<const short8*>(&As[w * 32 + 16 + lr][kc + lk]);
#pragma unroll
        for (int nb = 0; nb < 4; nb++) {
            short8 bf = *reinterpret_cast<const short8*>(&Ws[nb * 16 + lr][kc + lk]);
            acc[0][nb] = __builtin_amdgcn_mfma_f32_16x16x32_bf16(a0, bf, acc[0][nb], 0, 0, 0);
            acc[1][nb] = __builtin_amdgcn_mfma_f32_16x16x32_bf16(a1, bf, acc[1][nb], 0, 0, 0);
        }
    }
#pragma unroll
    for (int m = 0; m < 2; m++)
#pragma unroll
        for (int j = 0; j < 4; j++) {
            int r = row0 + w * 32 + m * 16 + (l >> 4) * 4 + j;
            if (r < n) {
#pragma unroll
                for (int nb = 0; nb < 4; nb++)
                    Y[(size_t)r * 64 + nb * 16 + lr] = f2bf(acc[m][nb][j]);
            }
        }
}

__global__ void k_attn2(const uint* __restrict__ hu, const float* __restrict__ a_src,
                        const float* __restrict__ a_dst, float* __restrict__ asrc,
                        float* __restrict__ adst, int n) {
    int t = blockIdx.x * 256 + threadIdx.x;
    if (t >= n * 8) return;
    int node = t >> 3, j = t & 7;
    const uint* hp = hu + (size_t)node * 32 + j * 4;
    float s1 = 0.f, s2 = 0.f;
#pragma unroll
    for (int q = 0; q < 4; q++) {
        uint u = hp[q];
        float v0 = bflo(u), v1 = bfhi(u);
        s1 = fmaf(v0, a_src[j * 8 + 2 * q], s1);
        s1 = fmaf(v1, a_src[j * 8 + 2 * q + 1], s1);
        s2 = fmaf(v0, a_dst[j * 8 + 2 * q], s2);
        s2 = fmaf(v1, a_dst[j * 8 + 2 * q + 1], s2);
    }
#pragma unroll
    for (int o = 1; o < 8; o <<= 1) {
        s1 += __shfl_xor(s1, o);
        s2 += __shfl_xor(s2, o);
    }
    if (j == 0) { asrc[node] = s1 * LOG2E; adst[node] = s2 * LOG2E; }
}

// ------------------------ aggregation --------------------------------------
// conv1: one wave per dst. Per 64-slot block: (1) coalesced vidx fetch,
// (2) PREFETCH first-16 edge h-rows (independent of P, stays in flight
// across the lgkm barrier), (3) cnt-bounded p-phase into LDS, (4) lgkmcnt(0),
// (5) fma loop: prefetched rows for j<16, loads beyond.
__global__ __launch_bounds__(256) void k_agg1(
    const uint* __restrict__ hu, const _Float16* __restrict__ asrc,
    const _Float16* __restrict__ adst, const int* __restrict__ rowptr,
    const int* __restrict__ csr, const float* __restrict__ b1,
    uint* __restrict__ x2, int n) {
    __shared__ float P[4][512];
    int wv = threadIdx.x >> 6;
    int wid = (blockIdx.x * 256 + threadIdx.x) >> 6;
    if (wid >= n) return;
    uint lane = threadIdx.x & 63;
    uint hd = lane >> 3;
    uint sl = lane & 7;
    uint c0 = lane * 2;
    float adn = (float)adst[(uint)wid * 8u + hd];
    int beg = rowptr[wid], end = rowptr[wid + 1];
    float s = 0.f, acc0 = 0.f, acc1 = 0.f;
    for (int base = beg; base < end; base += 64) {
        int cnt = min(64, end - base);
        int vidx = ((int)lane < cnt) ? csr[base + lane] : 0;
        int lim = cnt < 16 ? cnt : 16;
        // --- prefetch first-16 edge rows (vmem, unordered by lgkm barrier) ---
        uint pf[16];
#pragma unroll
        for (int i = 0; i < 16; i++) {
            if (i < lim) {
                uint si = __builtin_amdgcn_readlane(vidx, i);
                pf[i] = hu[si * 64u + lane];
            }
        }
        // --- p-phase: ceil(cnt/8) slot-groups, fp16 scores ---
        int mb = (cnt + 7) >> 3;
        for (int m = 0; m < mb; m++) {
            int slot = 8 * m + (int)sl;
            int cs = csr[base + min(slot, cnt - 1)];
            float e = (float)asrc[(uint)cs * 8u + hd] + adn;
            e = fmaxf(e, 0.2f * e);
            P[wv][slot * 8 + hd] = exp2f(e);
        }
        asm volatile("s_waitcnt lgkmcnt(0)" ::: "memory");
        // --- fma loop: prefetched window ---
#pragma unroll
        for (int j = 0; j < 16; j++) {
            if (j < lim) {
                float q = P[wv][j * 8 + hd];
                uint u = pf[j];
                s += q;
                acc0 = fmaf(q, bflo(u), acc0);
                acc1 = fmaf(q, bfhi(u), acc1);
            }
        }
        // --- beyond-16 edges ---
        int j = 16;
        for (; j + 8 <= cnt; j += 8) {
            uint s0 = __builtin_amdgcn_readlane(vidx, j);
            uint s1 = __builtin_amdgcn_readlane(vidx, j + 1);
            uint s2 = __builtin_amdgcn_readlane(vidx, j + 2);
            uint s3 = __builtin_amdgcn_readlane(vidx, j + 3);
            uint s4 = __builtin_amdgcn_readlane(vidx, j + 4);
            uint s5 = __builtin_amdgcn_readlane(vidx, j + 5);
            uint s6 = __builtin_amdgcn_readlane(vidx, j + 6);
            uint s7 = __builtin_amdgcn_readlane(vidx, j + 7);
            uint u0 = hu[s0 * 64u + lane];
            uint u1 = hu[s1 * 64u + lane];
            uint u2 = hu[s2 * 64u + lane];
            uint u3 = hu[s3 * 64u + lane];
            uint u4 = hu[s4 * 64u + lane];
            uint u5 = hu[s5 * 64u + lane];
            uint u6 = hu[s6 * 64u + lane];
            uint u7 = hu[s7 * 64u + lane];
            float q0 = P[wv][(j + 0) * 8 + hd];
            float q1 = P[wv][(j + 1) * 8 + hd];
            float q2 = P[wv][(j + 2) * 8 + hd];
            float q3 = P[wv][(j + 3) * 8 + hd];
            float q4 = P[wv][(j + 4) * 8 + hd];
            float q5 = P[wv][(j + 5) * 8 + hd];
            float q6 = P[wv][(j + 6) * 8 + hd];
            float q7 = P[wv][(j + 7) * 8 + hd];
            s += ((q0 + q1) + (q2 + q3)) + ((q4 + q5) + (q6 + q7));
            acc0 = fmaf(q0, bflo(u0), fmaf(q1, bflo(u1), acc0));
            acc0 = fmaf(q2, bflo(u2), fmaf(q3, bflo(u3), acc0));
            acc0 = fmaf(q4, bflo(u4), fmaf(q5, bflo(u5), acc0));
            acc0 = fmaf(q6, bflo(u6), fmaf(q7, bflo(u7), acc0));
            acc1 = fmaf(q0, bfhi(u0), fmaf(q1, bfhi(u1), acc1));
            acc1 = fmaf(q2, bfhi(u2), fmaf(q3, bfhi(u3), acc1));
            acc1 = fmaf(q4, bfhi(u4), fmaf(q5, bfhi(u5), acc1));
            acc1 = fmaf(q6, bfhi(u6), fmaf(q7, bfhi(u7), acc1));
        }
        for (; j < cnt; ++j) {
            uint s0 = __builtin_amdgcn_readlane(vidx, j);
            float q0 = P[wv][j * 8 + hd];
            uint u0 = hu[s0 * 64u + lane];
            s += q0;
            acc0 = fmaf(q0, bflo(u0), acc0);
            acc1 = fmaf(q0, bfhi(u0), acc1);
        }
    }
    float inv = 1.f / (s + 1e-16f);
    float o0 = acc0 * inv + b1[c0];
    float o1 = acc1 * inv + b1[c0 + 1];
    o0 = o0 > 0.f ? o0 : (__expf(o0) - 1.f);  // ELU
    o1 = o1 > 0.f ? o1 : (__expf(o1) - 1.f);
    union { ushort b[2]; uint u; } pk;
    pk.b[0] = f2bf(o0);
    pk.b[1] = f2bf(o1);
    x2[(uint)wid * 64u + lane] = pk.u;
}

// conv2: same prefetch structure; p from lane's own slot.
__global__ __launch_bounds__(256) void k_agg2(
    const ushort* __restrict__ hb, const float* __restrict__ asrc,
    const float* __restrict__ adst, const int* __restrict__ rowptr,
    const int* __restrict__ csr, const float* __restrict__ b2,
    float* __restrict__ out, int n) {
    __shared__ float P2[4][64];
    int wv = threadIdx.x >> 6;
    int wid = (blockIdx.x * 256 + threadIdx.x) >> 6;
    if (wid >= n) return;
    uint lane = threadIdx.x & 63;
    float adn = adst[wid];
    int beg = rowptr[wid], end = rowptr[wid + 1];
    float s = 0.f, acc = 0.f;
    for (int base = beg; base < end; base += 64) {
        int cnt = min(64, end - base);
        int vidx = csr[base + min((int)lane, cnt - 1)];
        int lim = cnt < 16 ? cnt : 16;
        // --- prefetch first-16 rows ---
        ushort pf[16];
#pragma unroll
        for (int i = 0; i < 16; i++) {
            if (i < lim) {
                uint si = __builtin_amdgcn_readlane(vidx, i);
                pf[i] = hb[si * 64u + lane];
            }
        }
        // --- p-phase ---
        float e = asrc[vidx] + adn;
        e = fmaxf(e, 0.2f * e);
        P2[wv][lane] = ((int)lane < cnt) ? exp2f(e) : 0.f;
        asm volatile("s_waitcnt lgkmcnt(0)" ::: "memory");
        // --- fma loop: prefetched window ---
#pragma unroll
        for (int j = 0; j < 16; j++) {
            if (j < lim) {
                float q = P2[wv][j];
                s += q;
                acc = fmaf(q, bf1(pf[j]), acc);
            }
        }
        int j = 16;
        for (; j + 8 <= cnt; j += 8) {
            uint s0 = __builtin_amdgcn_readlane(vidx, j);
            uint s1 = __builtin_amdgcn_readlane(vidx, j + 1);
            uint s2 = __builtin_amdgcn_readlane(vidx, j + 2);
            uint s3 = __builtin_amdgcn_readlane(vidx, j + 3);
            uint s4 = __builtin_amdgcn_readlane(vidx, j + 4);
            uint s5 = __builtin_amdgcn_readlane(vidx, j + 5);
            uint s6 = __builtin_amdgcn_readlane(vidx, j + 6);
            uint s7 = __builtin_amdgcn_readlane(vidx, j + 7);
            float h0 = bf1(hb[s0 * 64u + lane]);
            float h1 = bf1(hb[s1 * 64u + lane]);
            float h2 = bf1(hb[s2 * 64u + lane]);
            float h3 = bf1(hb[s3 * 64u + lane]);
            float h4 = bf1(hb[s4 * 64u + lane]);
            float h5 = bf1(hb[s5 * 64u + lane]);
            float h6 = bf1(hb[s6 * 64u + lane]);
            float h7 = bf1(hb[s7 * 64u + lane]);
            float q0 = P2[wv][j + 0];
            float q1 = P2[wv][j + 1];
            float q2 = P2[wv][j + 2];
            float q3 = P2[wv][j + 3];
            float q4 = P2[wv][j + 4];
            float q5 = P2[wv][j + 5];
            float q6 = P2[wv][j + 6];
            float q7 = P2[wv][j + 7];
            s += ((q0 + q1) + (q2 + q3)) + ((q4 + q5) + (q6 + q7));
            acc = fmaf(q0, h0, fmaf(q1, h1, acc));
            acc = fmaf(q2, h2, fmaf(q3, h3, acc));
            acc = fmaf(q4, h4, fmaf(q5, h5, acc));
            acc = fmaf(q6, h6, fmaf(q7, h7, acc));
        }
        for (; j < cnt; ++j) {
            uint s0 = __builtin_amdgcn_readlane(vidx, j);
            float q0 = P2[wv][j];
            float h0 = bf1(hb[s0 * 64u + lane]);
            s += q0;
            acc = fmaf(q0, h0, acc);
        }
    }
    out[(size_t)wid * 64 + lane] = acc / (s + 1e-16f) + b2[lane];
}

// ------------------------------- launch -------------------------------------
extern "C" void kernel_launch(void* const* d_in, const int* in_sizes, int n_in,
                              void* d_out, int out_size, void* d_ws, size_t ws_size,
                              hipStream_t stream) {
    const float* x   = (const float*)d_in[0];
    const int*   ei  = (const int*)d_in[1];
    const float* W1  = (const float*)d_in[2];
    const float* as1 = (const float*)d_in[3];
    const float* ad1 = (const float*)d_in[4];
    const float* b1  = (const float*)d_in[5];
    const float* W2  = (const float*)d_in[6];
    const float* as2 = (const float*)d_in[7];
    const float* ad2 = (const float*)d_in[8];
    const float* b2  = (const float*)d_in[9];
    float* out = (float*)d_out;

    int N = in_sizes[0] / 128;
    int E = in_sizes[1] / 2;
    int TOT = E + N;
    const int* src = ei;
    const int* dst = ei + E;

    char* p = (char*)d_ws;
    auto alloc = [&](size_t bytes) {
        char* r = p;
        p += (bytes + 255) & ~size_t(255);
        return r;
    };
    ushort* h1b  = (ushort*)alloc((size_t)N * 128 * 2);
    ushort* h2b  = (ushort*)alloc((size_t)N * 64 * 2);
    ushort* x2b  = (ushort*)alloc((size_t)N * 128 * 2);
    _Float16* asrc1 = (_Float16*)alloc((size_t)N * 8 * 2);
    _Float16* adst1 = (_Float16*)alloc((size_t)N * 8 * 2);
    float* asrc2 = (float*)alloc((size_t)N * 4);
    float* adst2 = (float*)alloc((size_t)N * 4);
    int* rowptr  = (int*)alloc((size_t)(N + 1) * 4);
    int* csr     = (int*)alloc((size_t)TOT * 4);
    int* ebuf    = (int*)alloc((size_t)E * 4);
    int* bcount  = (int*)alloc(1024 * 4);
    int* ebase   = (int*)alloc(1024 * 4);
    int* ecur    = (int*)alloc(1024 * 4);
    int* cbase   = (int*)alloc(1024 * 4);

    int NB = (N + 127) >> 7;
    int nbp = (E + 8191) / 8192;
    int gb = (N + 127) / 128;

    hipMemsetAsync(bcount, 0, 1024 * 4, stream);
    k_gemm1_bhist<<<nbp + gb, 256, 0, stream>>>(x, W1, h1b, N, dst, E, bcount, nbp);
    k_bscan_attn1<<<1 + (N * 8 + 255) / 256, 256, 0, stream>>>(
        bcount, NB, N, ebase, ecur, cbase, (const uint*)h1b, as1, ad1, asrc1, adst1);
    k_part<<<nbp, 512, 0, stream>>>(src, dst, E, ecur, ebuf);
    k_build<<<NB, 256, 0, stream>>>(ebuf, bcount, ebase, cbase, rowptr, csr, N, NB);
    k_agg1<<<(N + 3) / 4, 256, 0, stream>>>((const uint*)h1b, asrc1, adst1, rowptr, csr, b1,
                                            (uint*)x2b, N);
    k_gemm2<<<gb, 256, 0, stream>>>(x2b, W2, h2b, N);
    k_attn2<<<(N * 8 + 255) / 256, 256, 0, stream>>>((const uint*)h2b, as2, ad2, asrc2, adst2, N);
    k_agg2<<<(N + 3) / 4, 256, 0, stream>>>((const ushort*)h2b, asrc2, adst2, rowptr, csr, b2,
                                            out, N);
}

// Round 13
// 229.188 us; speedup vs baseline: 1.4702x; 1.4702x over previous
//
#include <hip/hip_runtime.h>
#include <hip/hip_bf16.h>
#include <math.h>

// ---------------------------------------------------------------------------
// 2-layer GAT on MI355X.
// R13: R11 skeleton; p1 (conv1 softmax numerators, fp16) computed inside
// k_build's copy-out loop (csr_l/dst_l already in LDS, coalesced 16B p1
// stores); agg1 reverted to the validated R9 streamed-p gather loop (69us).
// agg2 keeps R11's inline one-exp2-per-slot p-phase (asrc2 is L2-resident).
// R12's conditional register prefetch REMOVED (lengthened critical path).
// ---------------------------------------------------------------------------

typedef __attribute__((ext_vector_type(8))) short short8;
typedef __attribute__((ext_vector_type(4))) float f32x4;

__device__ __forceinline__ float bflo(uint u) { return __uint_as_float(u << 16); }
__device__ __forceinline__ float bfhi(uint u) { return __uint_as_float(u & 0xffff0000u); }
__device__ __forceinline__ float bf1(ushort v) { return __uint_as_float(((uint)v) << 16); }
__device__ __forceinline__ ushort f2bf(float f) {  // RNE f32->bf16
    uint u = __float_as_uint(f);
    u += 0x7fff + ((u >> 16) & 1);
    return (ushort)(u >> 16);
}
#define LOG2E 1.44269504088896f
#define CSR_CAP 4096

// ---------------- K_A: fused bucket-histogram + conv1 GEMM -----------------
__global__ __launch_bounds__(256) void k_gemm1_bhist(
    const float* __restrict__ X, const float* __restrict__ W,
    ushort* __restrict__ Y, int n,
    const int* __restrict__ dst, int e, int* __restrict__ bcount, int nbh) {
    __shared__ union {
        struct { ushort As[128][136]; ushort Ws[128][136]; } g;
        int h[1024];
    } sm;
    const int t = threadIdx.x;
    if ((int)blockIdx.x < nbh) {
        for (int i = t; i < 1024; i += 256) sm.h[i] = 0;
        __syncthreads();
        int c0 = blockIdx.x * 8192, c1 = min(c0 + 8192, e);
        for (int i = c0 + t; i < c1; i += 256) atomicAdd(&sm.h[dst[i] >> 7], 1);
        __syncthreads();
        for (int i = t; i < 1024; i += 256)
            if (sm.h[i]) atomicAdd(&bcount[i], sm.h[i]);
        return;
    }
    const int row0 = (blockIdx.x - nbh) * 128;
#pragma unroll
    for (int q = 0; q < 16; q++) {
        int idx = t + q * 256;
        int r = idx >> 5, c4 = (idx & 31) * 4;
        float4 xv = make_float4(0.f, 0.f, 0.f, 0.f);
        if (row0 + r < n) xv = *reinterpret_cast<const float4*>(&X[(size_t)(row0 + r) * 128 + c4]);
        ushort4 w4 = make_ushort4(f2bf(xv.x), f2bf(xv.y), f2bf(xv.z), f2bf(xv.w));
        *reinterpret_cast<ushort4*>(&sm.g.As[r][c4]) = w4;
    }
    for (int i = t; i < 128 * 128; i += 256) {
        int k = i >> 7, nc = i & 127;
        sm.g.Ws[nc][k] = f2bf(W[i]);
    }
    __syncthreads();
    const int w = t >> 6, l = t & 63;
    const int lr = l & 15;
    const int lk = (l >> 4) * 8;
    f32x4 acc[2][8];
#pragma unroll
    for (int m = 0; m < 2; m++)
#pragma unroll
        for (int nb = 0; nb < 8; nb++) acc[m][nb] = (f32x4){0.f, 0.f, 0.f, 0.f};
#pragma unroll
    for (int kc = 0; kc < 128; kc += 32) {
        short8 a0 = *reinterpret_cast<const short8*>(&sm.g.As[w * 32 + lr][kc + lk]);
        short8 a1 = *reinterpret_cast<const short8*>(&sm.g.As[w * 32 + 16 + lr][kc + lk]);
#pragma unroll
        for (int nb = 0; nb < 8; nb++) {
            short8 bf = *reinterpret_cast<const short8*>(&sm.g.Ws[nb * 16 + lr][kc + lk]);
            acc[0][nb] = __builtin_amdgcn_mfma_f32_16x16x32_bf16(a0, bf, acc[0][nb], 0, 0, 0);
            acc[1][nb] = __builtin_amdgcn_mfma_f32_16x16x32_bf16(a1, bf, acc[1][nb], 0, 0, 0);
        }
    }
#pragma unroll
    for (int m = 0; m < 2; m++)
#pragma unroll
        for (int j = 0; j < 4; j++) {
            int r = row0 + w * 32 + m * 16 + (l >> 4) * 4 + j;
            if (r < n) {
#pragma unroll
                for (int nb = 0; nb < 8; nb++)
                    Y[(size_t)r * 128 + nb * 16 + lr] = f2bf(acc[m][nb][j]);
            }
        }
}

// ---------------- K_B: fused bucket-scan + conv1 attention (fp16 out) ------
__global__ __launch_bounds__(256) void k_bscan_attn1(
    const int* __restrict__ bcount, int nb, int n,
    int* __restrict__ ebase, int* __restrict__ ecur, int* __restrict__ cbase,
    const uint* __restrict__ hu, const float* __restrict__ a_src,
    const float* __restrict__ a_dst, _Float16* __restrict__ asrc,
    _Float16* __restrict__ adst) {
    __shared__ int ae[1024], be[1024], ac[1024], bc[1024];
    int t = threadIdx.x;
    if (blockIdx.x == 0) {
        for (int i = t; i < 1024; i += 256) {
            int v = 0, nn = 0;
            if (i < nb) {
                v = bcount[i];
                nn = min(128, n - (i << 7));
            }
            ae[i] = v;
            ac[i] = v + nn;
        }
        __syncthreads();
        int* pa = ae; int* qa = be; int* pc = ac; int* qc = bc;
        for (int off = 1; off < 1024; off <<= 1) {
            for (int i = t; i < 1024; i += 256) {
                int va = pa[i], vc = pc[i];
                if (i >= off) { va += pa[i - off]; vc += pc[i - off]; }
                qa[i] = va; qc[i] = vc;
            }
            __syncthreads();
            int* tm = pa; pa = qa; qa = tm;
            tm = pc; pc = qc; qc = tm;
        }
        for (int i = t; i < 1024; i += 256) {
            if (i < nb) {
                int ea = (i == 0) ? 0 : pa[i - 1];
                int ca = (i == 0) ? 0 : pc[i - 1];
                ebase[i] = ea; ecur[i] = ea; cbase[i] = ca;
            }
        }
        return;
    }
    int tt = (blockIdx.x - 1) * 256 + t;
    if (tt >= n * 8) return;
    int node = tt >> 3, hd = tt & 7;
    const uint* hp = hu + (size_t)node * 64 + hd * 8;
    float s1 = 0.f, s2 = 0.f;
#pragma unroll
    for (int q = 0; q < 8; q++) {
        uint u = hp[q];
        float v0 = bflo(u), v1 = bfhi(u);
        s1 = fmaf(v0, a_src[hd * 16 + 2 * q], s1);
        s1 = fmaf(v1, a_src[hd * 16 + 2 * q + 1], s1);
        s2 = fmaf(v0, a_dst[hd * 16 + 2 * q], s2);
        s2 = fmaf(v1, a_dst[hd * 16 + 2 * q + 1], s2);
    }
    asrc[tt] = (_Float16)(s1 * LOG2E);
    adst[tt] = (_Float16)(s2 * LOG2E);
}

// ---------------- partition (unchanged) ------------------------------------
__global__ __launch_bounds__(512) void k_part(const int* __restrict__ src,
                                              const int* __restrict__ dst, int e,
                                              int* __restrict__ ecur, int* __restrict__ ebuf) {
    __shared__ int h[1024];
    __shared__ int base[1024];
    int t = threadIdx.x;
    int c0 = blockIdx.x * 8192, c1 = min(c0 + 8192, e);
    for (int i = t; i < 1024; i += 512) h[i] = 0;
    __syncthreads();
    for (int i = c0 + t; i < c1; i += 512) atomicAdd(&h[dst[i] >> 7], 1);
    __syncthreads();
    for (int i = t; i < 1024; i += 512) {
        int c = h[i];
        base[i] = c ? atomicAdd(&ecur[i], c) : 0;
        h[i] = 0;
    }
    __syncthreads();
    for (int i = c0 + t; i < c1; i += 512) {
        int d = dst[i], b = d >> 7;
        int r = atomicAdd(&h[b], 1);
        ebuf[base[b] + r] = (src[i] << 7) | (d & 127);
    }
}

// ---------------- build + fused p1 compute ---------------------------------
// p1[slot][hd] = exp2(leaky(asrc[src][hd] + adst[dst][hd])), fp16, written
// coalesced in the copy-out loop (csr_l/dst_l are in LDS).
__global__ __launch_bounds__(256) void k_build(const int* __restrict__ ebuf,
                                               const int* __restrict__ bcount,
                                               const int* __restrict__ ebase,
                                               const int* __restrict__ cbase,
                                               const _Float16* __restrict__ asrc,
                                               const _Float16* __restrict__ adst,
                                               int* __restrict__ rowptr,
                                               int* __restrict__ csr,
                                               _Float16* __restrict__ p1, int n, int nb) {
    __shared__ int cnt[128];
    __shared__ int sc[128], sc2[128];
    __shared__ int csr_l[CSR_CAP];
    __shared__ int dst_l[CSR_CAP];
    int b = blockIdx.x, t = threadIdx.x;
    int n0 = b << 7;
    int nn = min(128, n - n0);
    int ec = bcount[b], eb = ebase[b], cb = cbase[b];
    if (t < 128) cnt[t] = 0;
    __syncthreads();
    for (int i = t; i < ec; i += 256) atomicAdd(&cnt[ebuf[eb + i] & 127], 1);
    __syncthreads();
    if (t < 128) sc[t] = (t < nn) ? cnt[t] + 1 : 0;
    __syncthreads();
    int* p = sc; int* q = sc2;
    for (int off = 1; off < 128; off <<= 1) {
        if (t < 128) {
            int v = p[t];
            if (t >= off) v += p[t - off];
            q[t] = v;
        }
        __syncthreads();
        int* tm = p; p = q; q = tm;
    }
    int total = p[127];  // == ec + nn
    if (total <= CSR_CAP) {
        if (t < nn) {
            int off = (t == 0) ? 0 : p[t - 1];
            rowptr[n0 + t] = cb + off;
            csr_l[off] = n0 + t;   // self-loop
            dst_l[off] = n0 + t;
            cnt[t] = off + 1;
        }
        __syncthreads();
        for (int i = t; i < ec; i += 256) {
            int v = ebuf[eb + i];
            int s = atomicAdd(&cnt[v & 127], 1);
            csr_l[s] = v >> 7;
            dst_l[s] = n0 + (v & 127);
        }
        __syncthreads();
        for (int i = t; i < total; i += 256) {
            int s = csr_l[i], d = dst_l[i];
            csr[cb + i] = s;
            const _Float16* pa = asrc + (size_t)s * 8;
            const _Float16* pb = adst + (size_t)d * 8;
            _Float16 buf[8];
#pragma unroll
            for (int h = 0; h < 8; h++) {
                float e = (float)pa[h] + (float)pb[h];
                e = fmaxf(e, 0.2f * e);
                buf[h] = (_Float16)exp2f(e);
            }
            *reinterpret_cast<uint4*>(&p1[(size_t)(cb + i) * 8]) =
                *reinterpret_cast<const uint4*>(buf);
        }
    } else {  // fallback (never taken for random graphs)
        if (t < nn) {
            int off = (t == 0) ? 0 : p[t - 1];
            rowptr[n0 + t] = cb + off;
            csr[cb + off] = n0 + t;
            cnt[t] = off + 1;
            const _Float16* pa = asrc + (size_t)(n0 + t) * 8;
            const _Float16* pb = adst + (size_t)(n0 + t) * 8;
            _Float16 buf[8];
#pragma unroll
            for (int h = 0; h < 8; h++) {
                float e = (float)pa[h] + (float)pb[h];
                e = fmaxf(e, 0.2f * e);
                buf[h] = (_Float16)exp2f(e);
            }
            *reinterpret_cast<uint4*>(&p1[(size_t)(cb + off) * 8]) =
                *reinterpret_cast<const uint4*>(buf);
        }
        __syncthreads();
        for (int i = t; i < ec; i += 256) {
            int v = ebuf[eb + i];
            int sidx = v >> 7, d = n0 + (v & 127);
            int s = atomicAdd(&cnt[v & 127], 1);
            csr[cb + s] = sidx;
            const _Float16* pa = asrc + (size_t)sidx * 8;
            const _Float16* pb = adst + (size_t)d * 8;
            _Float16 buf[8];
#pragma unroll
            for (int h = 0; h < 8; h++) {
                float e = (float)pa[h] + (float)pb[h];
                e = fmaxf(e, 0.2f * e);
                buf[h] = (_Float16)exp2f(e);
            }
            *reinterpret_cast<uint4*>(&p1[(size_t)(cb + s) * 8]) =
                *reinterpret_cast<const uint4*>(buf);
        }
    }
    if (b == nb - 1 && t == 0) rowptr[n] = cb + total;
}

// ---------------- conv2 GEMM + attn2 (unchanged) ---------------------------
__global__ __launch_bounds__(256) void k_gemm2(const ushort* __restrict__ X,
                                               const float* __restrict__ W,
                                               ushort* __restrict__ Y, int n) {
    __shared__ ushort As[128][136];
    __shared__ ushort Ws[64][136];
    const int t = threadIdx.x;
    const int row0 = blockIdx.x * 128;
#pragma unroll
    for (int q = 0; q < 8; q++) {
        int idx = t + q * 256;
        int r = idx >> 4, c8 = (idx & 15) * 8;
        uint4 v = make_uint4(0u, 0u, 0u, 0u);
        if (row0 + r < n) v = *reinterpret_cast<const uint4*>(&X[(size_t)(row0 + r) * 128 + c8]);
        *reinterpret_cast<uint4*>(&As[r][c8]) = v;
    }
    for (int i = t; i < 128 * 64; i += 256) {
        int k = i >> 6, nc = i & 63;
        Ws[nc][k] = f2bf(W[i]);
    }
    __syncthreads();
    const int w = t >> 6, l = t & 63;
    const int lr = l & 15;
    const int lk = (l >> 4) * 8;
    f32x4 acc[2][4];
#pragma unroll
    for (int m = 0; m < 2; m++)
#pragma unroll
        for (int nb = 0; nb < 4; nb++) acc[m][nb] = (f32x4){0.f, 0.f, 0.f, 0.f};
#pragma unroll
    for (int kc = 0; kc < 128; kc += 32) {
        short8 a0 = *reinterpret_cast<const short8*>(&As[w * 32 + lr][kc + lk]);
        short8 a1 = *reinterpret_cast<const short8*>(&As[w * 32 + 16 + lr][kc + lk]);
#pragma unroll
        for (int nb = 0; nb < 4; nb++) {
            short8 bf = *reinterpret_cast<const short8*>(&Ws[nb * 16 + lr][kc + lk]);
            acc[0][nb] = __builtin_amdgcn_mfma_f32_16x16x32_bf16(a0, bf, acc[0][nb], 0, 0, 0);
            acc[1][nb] = __builtin_amdgcn_mfma_f32_16x16x32_bf16(a1, bf, acc[1][nb], 0, 0, 0);
        }
    }
#pragma unroll
    for (int m = 0; m < 2; m++)
#pragma unroll
        for (int j = 0; j < 4; j++) {
            int r = row0 + w * 32 + m * 16 + (l >> 4) * 4 + j;
            if (r < n) {
#pragma unroll
                for (int nb = 0; nb < 4; nb++)
                    Y[(size_t)r * 64 + nb * 16 + lr] = f2bf(acc[m][nb][j]);
            }
        }
}

__global__ void k_attn2(const uint* __restrict__ hu, const float* __restrict__ a_src,
                        const float* __restrict__ a_dst, float* __restrict__ asrc,
                        float* __restrict__ adst, int n) {
    int t = blockIdx.x * 256 + threadIdx.x;
    if (t >= n * 8) return;
    int node = t >> 3, j = t & 7;
    const uint* hp = hu + (size_t)node * 32 + j * 4;
    float s1 = 0.f, s2 = 0.f;
#pragma unroll
    for (int q = 0; q < 4; q++) {
        uint u = hp[q];
        float v0 = bflo(u), v1 = bfhi(u);
        s1 = fmaf(v0, a_src[j * 8 + 2 * q], s1);
        s1 = fmaf(v1, a_src[j * 8 + 2 * q + 1], s1);
        s2 = fmaf(v0, a_dst[j * 8 + 2 * q], s2);
        s2 = fmaf(v1, a_dst[j * 8 + 2 * q + 1], s2);
    }
#pragma unroll
    for (int o = 1; o < 8; o <<= 1) {
        s1 += __shfl_xor(s1, o);
        s2 += __shfl_xor(s2, o);
    }
    if (j == 0) { asrc[node] = s1 * LOG2E; adst[node] = s2 * LOG2E; }
}

// ------------------------ aggregation --------------------------------------
// conv1 (R9 structure): one wave per dst; coalesced csr fetch + readlane
// broadcast; p1 streamed with immediate-offset fp16 loads; unroll 8.
__global__ __launch_bounds__(256) void k_agg1(
    const uint* __restrict__ hu, const _Float16* __restrict__ p1,
    const int* __restrict__ rowptr, const int* __restrict__ csr,
    const float* __restrict__ b1, uint* __restrict__ x2, int n) {
    int wid = (blockIdx.x * 256 + threadIdx.x) >> 6;
    if (wid >= n) return;
    uint lane = threadIdx.x & 63;
    uint c0 = lane * 2;
    uint hd = lane >> 3;
    int beg = rowptr[wid], end = rowptr[wid + 1];
    float s = 0.f, acc0 = 0.f, acc1 = 0.f;
    for (int base = beg; base < end; base += 64) {
        int cnt = min(64, end - base);
        int vidx = ((int)lane < cnt) ? csr[base + lane] : 0;
        const _Float16* pp = p1 + (size_t)base * 8 + hd;
        int j = 0;
        for (; j + 8 <= cnt; j += 8) {
            uint s0 = __builtin_amdgcn_readlane(vidx, j);
            uint s1 = __builtin_amdgcn_readlane(vidx, j + 1);
            uint s2 = __builtin_amdgcn_readlane(vidx, j + 2);
            uint s3 = __builtin_amdgcn_readlane(vidx, j + 3);
            uint s4 = __builtin_amdgcn_readlane(vidx, j + 4);
            uint s5 = __builtin_amdgcn_readlane(vidx, j + 5);
            uint s6 = __builtin_amdgcn_readlane(vidx, j + 6);
            uint s7 = __builtin_amdgcn_readlane(vidx, j + 7);
            uint u0 = hu[s0 * 64u + lane];
            uint u1 = hu[s1 * 64u + lane];
            uint u2 = hu[s2 * 64u + lane];
            uint u3 = hu[s3 * 64u + lane];
            uint u4 = hu[s4 * 64u + lane];
            uint u5 = hu[s5 * 64u + lane];
            uint u6 = hu[s6 * 64u + lane];
            uint u7 = hu[s7 * 64u + lane];
            float q0 = (float)pp[(j + 0) * 8];
            float q1 = (float)pp[(j + 1) * 8];
            float q2 = (float)pp[(j + 2) * 8];
            float q3 = (float)pp[(j + 3) * 8];
            float q4 = (float)pp[(j + 4) * 8];
            float q5 = (float)pp[(j + 5) * 8];
            float q6 = (float)pp[(j + 6) * 8];
            float q7 = (float)pp[(j + 7) * 8];
            s += ((q0 + q1) + (q2 + q3)) + ((q4 + q5) + (q6 + q7));
            acc0 = fmaf(q0, bflo(u0), fmaf(q1, bflo(u1), acc0));
            acc0 = fmaf(q2, bflo(u2), fmaf(q3, bflo(u3), acc0));
            acc0 = fmaf(q4, bflo(u4), fmaf(q5, bflo(u5), acc0));
            acc0 = fmaf(q6, bflo(u6), fmaf(q7, bflo(u7), acc0));
            acc1 = fmaf(q0, bfhi(u0), fmaf(q1, bfhi(u1), acc1));
            acc1 = fmaf(q2, bfhi(u2), fmaf(q3, bfhi(u3), acc1));
            acc1 = fmaf(q4, bfhi(u4), fmaf(q5, bfhi(u5), acc1));
            acc1 = fmaf(q6, bfhi(u6), fmaf(q7, bfhi(u7), acc1));
        }
        for (; j < cnt; ++j) {
            uint s0 = __builtin_amdgcn_readlane(vidx, j);
            float q0 = (float)pp[j * 8];
            uint u0 = hu[s0 * 64u + lane];
            s += q0;
            acc0 = fmaf(q0, bflo(u0), acc0);
            acc1 = fmaf(q0, bfhi(u0), acc1);
        }
    }
    float inv = 1.f / (s + 1e-16f);
    float o0 = acc0 * inv + b1[c0];
    float o1 = acc1 * inv + b1[c0 + 1];
    o0 = o0 > 0.f ? o0 : (__expf(o0) - 1.f);  // ELU
    o1 = o1 > 0.f ? o1 : (__expf(o1) - 1.f);
    union { ushort b[2]; uint u; } pk;
    pk.b[0] = f2bf(o0);
    pk.b[1] = f2bf(o1);
    x2[(uint)wid * 64u + lane] = pk.u;
}

// conv2 (R11 structure): inline single-exp2 p-phase into LDS, then gather.
__global__ __launch_bounds__(256) void k_agg2(
    const ushort* __restrict__ hb, const float* __restrict__ asrc,
    const float* __restrict__ adst, const int* __restrict__ rowptr,
    const int* __restrict__ csr, const float* __restrict__ b2,
    float* __restrict__ out, int n) {
    __shared__ float P2[4][64];
    int wv = threadIdx.x >> 6;
    int wid = (blockIdx.x * 256 + threadIdx.x) >> 6;
    if (wid >= n) return;
    uint lane = threadIdx.x & 63;
    float adn = adst[wid];
    int beg = rowptr[wid], end = rowptr[wid + 1];
    float s = 0.f, acc = 0.f;
    for (int base = beg; base < end; base += 64) {
        int cnt = min(64, end - base);
        int vidx = csr[base + min((int)lane, cnt - 1)];
        float e = asrc[vidx] + adn;
        e = fmaxf(e, 0.2f * e);
        P2[wv][lane] = ((int)lane < cnt) ? exp2f(e) : 0.f;
        asm volatile("s_waitcnt lgkmcnt(0)" ::: "memory");
        int j = 0;
        for (; j + 8 <= cnt; j += 8) {
            uint s0 = __builtin_amdgcn_readlane(vidx, j);
            uint s1 = __builtin_amdgcn_readlane(vidx, j + 1);
            uint s2 = __builtin_amdgcn_readlane(vidx, j + 2);
            uint s3 = __builtin_amdgcn_readlane(vidx, j + 3);
            uint s4 = __builtin_amdgcn_readlane(vidx, j + 4);
            uint s5 = __builtin_amdgcn_readlane(vidx, j + 5);
            uint s6 = __builtin_amdgcn_readlane(vidx, j + 6);
            uint s7 = __builtin_amdgcn_readlane(vidx, j + 7);
            float h0 = bf1(hb[s0 * 64u + lane]);
            float h1 = bf1(hb[s1 * 64u + lane]);
            float h2 = bf1(hb[s2 * 64u + lane]);
            float h3 = bf1(hb[s3 * 64u + lane]);
            float h4 = bf1(hb[s4 * 64u + lane]);
            float h5 = bf1(hb[s5 * 64u + lane]);
            float h6 = bf1(hb[s6 * 64u + lane]);
            float h7 = bf1(hb[s7 * 64u + lane]);
            float q0 = P2[wv][j + 0];
            float q1 = P2[wv][j + 1];
            float q2 = P2[wv][j + 2];
            float q3 = P2[wv][j + 3];
            float q4 = P2[wv][j + 4];
            float q5 = P2[wv][j + 5];
            float q6 = P2[wv][j + 6];
            float q7 = P2[wv][j + 7];
            s += ((q0 + q1) + (q2 + q3)) + ((q4 + q5) + (q6 + q7));
            acc = fmaf(q0, h0, fmaf(q1, h1, acc));
            acc = fmaf(q2, h2, fmaf(q3, h3, acc));
            acc = fmaf(q4, h4, fmaf(q5, h5, acc));
            acc = fmaf(q6, h6, fmaf(q7, h7, acc));
        }
        for (; j < cnt; ++j) {
            uint s0 = __builtin_amdgcn_readlane(vidx, j);
            float q0 = P2[wv][j];
            float h0 = bf1(hb[s0 * 64u + lane]);
            s += q0;
            acc = fmaf(q0, h0, acc);
        }
    }
    out[(size_t)wid * 64 + lane] = acc / (s + 1e-16f) + b2[lane];
}

// ------------------------------- launch -------------------------------------
extern "C" void kernel_launch(void* const* d_in, const int* in_sizes, int n_in,
                              void* d_out, int out_size, void* d_ws, size_t ws_size,
                              hipStream_t stream) {
    const float* x   = (const float*)d_in[0];
    const int*   ei  = (const int*)d_in[1];
    const float* W1  = (const float*)d_in[2];
    const float* as1 = (const float*)d_in[3];
    const float* ad1 = (const float*)d_in[4];
    const float* b1  = (const float*)d_in[5];
    const float* W2  = (const float*)d_in[6];
    const float* as2 = (const float*)d_in[7];
    const float* ad2 = (const float*)d_in[8];
    const float* b2  = (const float*)d_in[9];
    float* out = (float*)d_out;

    int N = in_sizes[0] / 128;
    int E = in_sizes[1] / 2;
    int TOT = E + N;
    const int* src = ei;
    const int* dst = ei + E;

    char* p = (char*)d_ws;
    auto alloc = [&](size_t bytes) {
        char* r = p;
        p += (bytes + 255) & ~size_t(255);
        return r;
    };
    ushort* h1b  = (ushort*)alloc((size_t)N * 128 * 2);
    ushort* h2b  = (ushort*)alloc((size_t)N * 64 * 2);
    ushort* x2b  = (ushort*)alloc((size_t)N * 128 * 2);
    _Float16* asrc1 = (_Float16*)alloc((size_t)N * 8 * 2);
    _Float16* adst1 = (_Float16*)alloc((size_t)N * 8 * 2);
    float* asrc2 = (float*)alloc((size_t)N * 4);
    float* adst2 = (float*)alloc((size_t)N * 4);
    int* rowptr  = (int*)alloc((size_t)(N + 1) * 4);
    int* csr     = (int*)alloc((size_t)TOT * 4);
    int* ebuf    = (int*)alloc((size_t)E * 4);
    _Float16* p1 = (_Float16*)alloc(((size_t)TOT * 8 + 16) * 2);
    int* bcount  = (int*)alloc(1024 * 4);
    int* ebase   = (int*)alloc(1024 * 4);
    int* ecur    = (int*)alloc(1024 * 4);
    int* cbase   = (int*)alloc(1024 * 4);

    int NB = (N + 127) >> 7;
    int nbp = (E + 8191) / 8192;
    int gb = (N + 127) / 128;

    hipMemsetAsync(bcount, 0, 1024 * 4, stream);
    k_gemm1_bhist<<<nbp + gb, 256, 0, stream>>>(x, W1, h1b, N, dst, E, bcount, nbp);
    k_bscan_attn1<<<1 + (N * 8 + 255) / 256, 256, 0, stream>>>(
        bcount, NB, N, ebase, ecur, cbase, (const uint*)h1b, as1, ad1, asrc1, adst1);
    k_part<<<nbp, 512, 0, stream>>>(src, dst, E, ecur, ebuf);
    k_build<<<NB, 256, 0, stream>>>(ebuf, bcount, ebase, cbase, asrc1, adst1,
                                    rowptr, csr, p1, N, NB);
    k_agg1<<<(N + 3) / 4, 256, 0, stream>>>((const uint*)h1b, p1, rowptr, csr, b1,
                                            (uint*)x2b, N);
    k_gemm2<<<gb, 256, 0, stream>>>(x2b, W2, h2b, N);
    k_attn2<<<(N * 8 + 255) / 256, 256, 0, stream>>>((const uint*)h2b, as2, ad2, asrc2, adst2, N);
    k_agg2<<<(N + 3) / 4, 256, 0, stream>>>((const ushort*)h2b, asrc2, adst2, rowptr, csr, b2,
                                            out, N);
}

// Round 14
// 228.515 us; speedup vs baseline: 1.4745x; 1.0029x over previous
//
#include <hip/hip_runtime.h>
#include <hip/hip_bf16.h>
#include <math.h>

// ---------------------------------------------------------------------------
// 2-layer GAT on MI355X.
// R14: (a) agg2 p computed per-lane IN REGISTER + readlane broadcast (no LDS
// barrier — removes R11-style chain serialization that cost agg1 18us);
// (b) attn2 fused into gemm2 epilogue (shfl-reduce over the 16-lane lr
// group; kills the attn2 dispatch + 12.8MB h2 re-read).
// Rest = R13: k_build-fused p1, R9 streamed-p agg1 (69us floor), bucket-sort
// CSR, fused {bhist||gemm1} {bscan||attn1}, MFMA GEMMs.
// ---------------------------------------------------------------------------

typedef __attribute__((ext_vector_type(8))) short short8;
typedef __attribute__((ext_vector_type(4))) float f32x4;

__device__ __forceinline__ float bflo(uint u) { return __uint_as_float(u << 16); }
__device__ __forceinline__ float bfhi(uint u) { return __uint_as_float(u & 0xffff0000u); }
__device__ __forceinline__ float bf1(ushort v) { return __uint_as_float(((uint)v) << 16); }
__device__ __forceinline__ ushort f2bf(float f) {  // RNE f32->bf16
    uint u = __float_as_uint(f);
    u += 0x7fff + ((u >> 16) & 1);
    return (ushort)(u >> 16);
}
#define LOG2E 1.44269504088896f
#define CSR_CAP 4096

// ---------------- K_A: fused bucket-histogram + conv1 GEMM -----------------
__global__ __launch_bounds__(256) void k_gemm1_bhist(
    const float* __restrict__ X, const float* __restrict__ W,
    ushort* __restrict__ Y, int n,
    const int* __restrict__ dst, int e, int* __restrict__ bcount, int nbh) {
    __shared__ union {
        struct { ushort As[128][136]; ushort Ws[128][136]; } g;
        int h[1024];
    } sm;
    const int t = threadIdx.x;
    if ((int)blockIdx.x < nbh) {
        for (int i = t; i < 1024; i += 256) sm.h[i] = 0;
        __syncthreads();
        int c0 = blockIdx.x * 8192, c1 = min(c0 + 8192, e);
        for (int i = c0 + t; i < c1; i += 256) atomicAdd(&sm.h[dst[i] >> 7], 1);
        __syncthreads();
        for (int i = t; i < 1024; i += 256)
            if (sm.h[i]) atomicAdd(&bcount[i], sm.h[i]);
        return;
    }
    const int row0 = (blockIdx.x - nbh) * 128;
#pragma unroll
    for (int q = 0; q < 16; q++) {
        int idx = t + q * 256;
        int r = idx >> 5, c4 = (idx & 31) * 4;
        float4 xv = make_float4(0.f, 0.f, 0.f, 0.f);
        if (row0 + r < n) xv = *reinterpret_cast<const float4*>(&X[(size_t)(row0 + r) * 128 + c4]);
        ushort4 w4 = make_ushort4(f2bf(xv.x), f2bf(xv.y), f2bf(xv.z), f2bf(xv.w));
        *reinterpret_cast<ushort4*>(&sm.g.As[r][c4]) = w4;
    }
    for (int i = t; i < 128 * 128; i += 256) {
        int k = i >> 7, nc = i & 127;
        sm.g.Ws[nc][k] = f2bf(W[i]);
    }
    __syncthreads();
    const int w = t >> 6, l = t & 63;
    const int lr = l & 15;
    const int lk = (l >> 4) * 8;
    f32x4 acc[2][8];
#pragma unroll
    for (int m = 0; m < 2; m++)
#pragma unroll
        for (int nb = 0; nb < 8; nb++) acc[m][nb] = (f32x4){0.f, 0.f, 0.f, 0.f};
#pragma unroll
    for (int kc = 0; kc < 128; kc += 32) {
        short8 a0 = *reinterpret_cast<const short8*>(&sm.g.As[w * 32 + lr][kc + lk]);
        short8 a1 = *reinterpret_cast<const short8*>(&sm.g.As[w * 32 + 16 + lr][kc + lk]);
#pragma unroll
        for (int nb = 0; nb < 8; nb++) {
            short8 bf = *reinterpret_cast<const short8*>(&sm.g.Ws[nb * 16 + lr][kc + lk]);
            acc[0][nb] = __builtin_amdgcn_mfma_f32_16x16x32_bf16(a0, bf, acc[0][nb], 0, 0, 0);
            acc[1][nb] = __builtin_amdgcn_mfma_f32_16x16x32_bf16(a1, bf, acc[1][nb], 0, 0, 0);
        }
    }
#pragma unroll
    for (int m = 0; m < 2; m++)
#pragma unroll
        for (int j = 0; j < 4; j++) {
            int r = row0 + w * 32 + m * 16 + (l >> 4) * 4 + j;
            if (r < n) {
#pragma unroll
                for (int nb = 0; nb < 8; nb++)
                    Y[(size_t)r * 128 + nb * 16 + lr] = f2bf(acc[m][nb][j]);
            }
        }
}

// ---------------- K_B: fused bucket-scan + conv1 attention (fp16 out) ------
__global__ __launch_bounds__(256) void k_bscan_attn1(
    const int* __restrict__ bcount, int nb, int n,
    int* __restrict__ ebase, int* __restrict__ ecur, int* __restrict__ cbase,
    const uint* __restrict__ hu, const float* __restrict__ a_src,
    const float* __restrict__ a_dst, _Float16* __restrict__ asrc,
    _Float16* __restrict__ adst) {
    __shared__ int ae[1024], be[1024], ac[1024], bc[1024];
    int t = threadIdx.x;
    if (blockIdx.x == 0) {
        for (int i = t; i < 1024; i += 256) {
            int v = 0, nn = 0;
            if (i < nb) {
                v = bcount[i];
                nn = min(128, n - (i << 7));
            }
            ae[i] = v;
            ac[i] = v + nn;
        }
        __syncthreads();
        int* pa = ae; int* qa = be; int* pc = ac; int* qc = bc;
        for (int off = 1; off < 1024; off <<= 1) {
            for (int i = t; i < 1024; i += 256) {
                int va = pa[i], vc = pc[i];
                if (i >= off) { va += pa[i - off]; vc += pc[i - off]; }
                qa[i] = va; qc[i] = vc;
            }
            __syncthreads();
            int* tm = pa; pa = qa; qa = tm;
            tm = pc; pc = qc; qc = tm;
        }
        for (int i = t; i < 1024; i += 256) {
            if (i < nb) {
                int ea = (i == 0) ? 0 : pa[i - 1];
                int ca = (i == 0) ? 0 : pc[i - 1];
                ebase[i] = ea; ecur[i] = ea; cbase[i] = ca;
            }
        }
        return;
    }
    int tt = (blockIdx.x - 1) * 256 + t;
    if (tt >= n * 8) return;
    int node = tt >> 3, hd = tt & 7;
    const uint* hp = hu + (size_t)node * 64 + hd * 8;
    float s1 = 0.f, s2 = 0.f;
#pragma unroll
    for (int q = 0; q < 8; q++) {
        uint u = hp[q];
        float v0 = bflo(u), v1 = bfhi(u);
        s1 = fmaf(v0, a_src[hd * 16 + 2 * q], s1);
        s1 = fmaf(v1, a_src[hd * 16 + 2 * q + 1], s1);
        s2 = fmaf(v0, a_dst[hd * 16 + 2 * q], s2);
        s2 = fmaf(v1, a_dst[hd * 16 + 2 * q + 1], s2);
    }
    asrc[tt] = (_Float16)(s1 * LOG2E);
    adst[tt] = (_Float16)(s2 * LOG2E);
}

// ---------------- partition (unchanged) ------------------------------------
__global__ __launch_bounds__(512) void k_part(const int* __restrict__ src,
                                              const int* __restrict__ dst, int e,
                                              int* __restrict__ ecur, int* __restrict__ ebuf) {
    __shared__ int h[1024];
    __shared__ int base[1024];
    int t = threadIdx.x;
    int c0 = blockIdx.x * 8192, c1 = min(c0 + 8192, e);
    for (int i = t; i < 1024; i += 512) h[i] = 0;
    __syncthreads();
    for (int i = c0 + t; i < c1; i += 512) atomicAdd(&h[dst[i] >> 7], 1);
    __syncthreads();
    for (int i = t; i < 1024; i += 512) {
        int c = h[i];
        base[i] = c ? atomicAdd(&ecur[i], c) : 0;
        h[i] = 0;
    }
    __syncthreads();
    for (int i = c0 + t; i < c1; i += 512) {
        int d = dst[i], b = d >> 7;
        int r = atomicAdd(&h[b], 1);
        ebuf[base[b] + r] = (src[i] << 7) | (d & 127);
    }
}

// ---------------- build + fused p1 compute (unchanged from R13) ------------
__global__ __launch_bounds__(256) void k_build(const int* __restrict__ ebuf,
                                               const int* __restrict__ bcount,
                                               const int* __restrict__ ebase,
                                               const int* __restrict__ cbase,
                                               const _Float16* __restrict__ asrc,
                                               const _Float16* __restrict__ adst,
                                               int* __restrict__ rowptr,
                                               int* __restrict__ csr,
                                               _Float16* __restrict__ p1, int n, int nb) {
    __shared__ int cnt[128];
    __shared__ int sc[128], sc2[128];
    __shared__ int csr_l[CSR_CAP];
    __shared__ int dst_l[CSR_CAP];
    int b = blockIdx.x, t = threadIdx.x;
    int n0 = b << 7;
    int nn = min(128, n - n0);
    int ec = bcount[b], eb = ebase[b], cb = cbase[b];
    if (t < 128) cnt[t] = 0;
    __syncthreads();
    for (int i = t; i < ec; i += 256) atomicAdd(&cnt[ebuf[eb + i] & 127], 1);
    __syncthreads();
    if (t < 128) sc[t] = (t < nn) ? cnt[t] + 1 : 0;
    __syncthreads();
    int* p = sc; int* q = sc2;
    for (int off = 1; off < 128; off <<= 1) {
        if (t < 128) {
            int v = p[t];
            if (t >= off) v += p[t - off];
            q[t] = v;
        }
        __syncthreads();
        int* tm = p; p = q; q = tm;
    }
    int total = p[127];  // == ec + nn
    if (total <= CSR_CAP) {
        if (t < nn) {
            int off = (t == 0) ? 0 : p[t - 1];
            rowptr[n0 + t] = cb + off;
            csr_l[off] = n0 + t;   // self-loop
            dst_l[off] = n0 + t;
            cnt[t] = off + 1;
        }
        __syncthreads();
        for (int i = t; i < ec; i += 256) {
            int v = ebuf[eb + i];
            int s = atomicAdd(&cnt[v & 127], 1);
            csr_l[s] = v >> 7;
            dst_l[s] = n0 + (v & 127);
        }
        __syncthreads();
        for (int i = t; i < total; i += 256) {
            int s = csr_l[i], d = dst_l[i];
            csr[cb + i] = s;
            const _Float16* pa = asrc + (size_t)s * 8;
            const _Float16* pb = adst + (size_t)d * 8;
            _Float16 buf[8];
#pragma unroll
            for (int h = 0; h < 8; h++) {
                float e = (float)pa[h] + (float)pb[h];
                e = fmaxf(e, 0.2f * e);
                buf[h] = (_Float16)exp2f(e);
            }
            *reinterpret_cast<uint4*>(&p1[(size_t)(cb + i) * 8]) =
                *reinterpret_cast<const uint4*>(buf);
        }
    } else {  // fallback (never taken for random graphs)
        if (t < nn) {
            int off = (t == 0) ? 0 : p[t - 1];
            rowptr[n0 + t] = cb + off;
            csr[cb + off] = n0 + t;
            cnt[t] = off + 1;
            const _Float16* pa = asrc + (size_t)(n0 + t) * 8;
            const _Float16* pb = adst + (size_t)(n0 + t) * 8;
            _Float16 buf[8];
#pragma unroll
            for (int h = 0; h < 8; h++) {
                float e = (float)pa[h] + (float)pb[h];
                e = fmaxf(e, 0.2f * e);
                buf[h] = (_Float16)exp2f(e);
            }
            *reinterpret_cast<uint4*>(&p1[(size_t)(cb + off) * 8]) =
                *reinterpret_cast<const uint4*>(buf);
        }
        __syncthreads();
        for (int i = t; i < ec; i += 256) {
            int v = ebuf[eb + i];
            int sidx = v >> 7, d = n0 + (v & 127);
            int s = atomicAdd(&cnt[v & 127], 1);
            csr[cb + s] = sidx;
            const _Float16* pa = asrc + (size_t)sidx * 8;
            const _Float16* pb = adst + (size_t)d * 8;
            _Float16 buf[8];
#pragma unroll
            for (int h = 0; h < 8; h++) {
                float e = (float)pa[h] + (float)pb[h];
                e = fmaxf(e, 0.2f * e);
                buf[h] = (_Float16)exp2f(e);
            }
            *reinterpret_cast<uint4*>(&p1[(size_t)(cb + s) * 8]) =
                *reinterpret_cast<const uint4*>(buf);
        }
    }
    if (b == nb - 1 && t == 0) rowptr[n] = cb + total;
}

// ---------------- conv2 GEMM with FUSED attn2 epilogue ---------------------
// Tile = 128 rows x 64 cols = complete h2 rows. Scores via per-(m,j) dot
// (8 fma) + shfl_xor reduce over the 16-lane lr group; lr==0 stores.
__global__ __launch_bounds__(256) void k_gemm2_attn2(
    const ushort* __restrict__ X, const float* __restrict__ W,
    ushort* __restrict__ Y,
    const float* __restrict__ a_src2, const float* __restrict__ a_dst2,
    float* __restrict__ asrc2, float* __restrict__ adst2, int n) {
    __shared__ ushort As[128][136];
    __shared__ ushort Ws[64][136];
    const int t = threadIdx.x;
    const int row0 = blockIdx.x * 128;
#pragma unroll
    for (int q = 0; q < 8; q++) {
        int idx = t + q * 256;
        int r = idx >> 4, c8 = (idx & 15) * 8;
        uint4 v = make_uint4(0u, 0u, 0u, 0u);
        if (row0 + r < n) v = *reinterpret_cast<const uint4*>(&X[(size_t)(row0 + r) * 128 + c8]);
        *reinterpret_cast<uint4*>(&As[r][c8]) = v;
    }
    for (int i = t; i < 128 * 64; i += 256) {
        int k = i >> 6, nc = i & 63;
        Ws[nc][k] = f2bf(W[i]);
    }
    __syncthreads();
    const int w = t >> 6, l = t & 63;
    const int lr = l & 15;
    const int lk = (l >> 4) * 8;
    f32x4 acc[2][4];
#pragma unroll
    for (int m = 0; m < 2; m++)
#pragma unroll
        for (int nb = 0; nb < 4; nb++) acc[m][nb] = (f32x4){0.f, 0.f, 0.f, 0.f};
#pragma unroll
    for (int kc = 0; kc < 128; kc += 32) {
        short8 a0 = *reinterpret_cast<const short8*>(&As[w * 32 + lr][kc + lk]);
        short8 a1 = *reinterpret_cast<const short8*>(&As[w * 32 + 16 + lr][kc + lk]);
#pragma unroll
        for (int nb = 0; nb < 4; nb++) {
            short8 bf = *reinterpret_cast<const short8*>(&Ws[nb * 16 + lr][kc + lk]);
            acc[0][nb] = __builtin_amdgcn_mfma_f32_16x16x32_bf16(a0, bf, acc[0][nb], 0, 0, 0);
            acc[1][nb] = __builtin_amdgcn_mfma_f32_16x16x32_bf16(a1, bf, acc[1][nb], 0, 0, 0);
        }
    }
    float av_s[4], av_d[4];
#pragma unroll
    for (int nb = 0; nb < 4; nb++) {
        av_s[nb] = a_src2[nb * 16 + lr];
        av_d[nb] = a_dst2[nb * 16 + lr];
    }
#pragma unroll
    for (int m = 0; m < 2; m++)
#pragma unroll
        for (int j = 0; j < 4; j++) {
            int r = row0 + w * 32 + m * 16 + (l >> 4) * 4 + j;
            float s1 = 0.f, s2 = 0.f;
#pragma unroll
            for (int nb = 0; nb < 4; nb++) {
                s1 = fmaf(acc[m][nb][j], av_s[nb], s1);
                s2 = fmaf(acc[m][nb][j], av_d[nb], s2);
            }
#pragma unroll
            for (int o = 1; o < 16; o <<= 1) {
                s1 += __shfl_xor(s1, o);
                s2 += __shfl_xor(s2, o);
            }
            if (r < n) {
#pragma unroll
                for (int nb = 0; nb < 4; nb++)
                    Y[(size_t)r * 64 + nb * 16 + lr] = f2bf(acc[m][nb][j]);
                if (lr == 0) {
                    asrc2[r] = s1 * LOG2E;
                    adst2[r] = s2 * LOG2E;
                }
            }
        }
}

// ------------------------ aggregation --------------------------------------
// conv1 (R9 structure, validated 69us floor): streamed fp16 p1, readlane
// index broadcast, unroll 8.
__global__ __launch_bounds__(256) void k_agg1(
    const uint* __restrict__ hu, const _Float16* __restrict__ p1,
    const int* __restrict__ rowptr, const int* __restrict__ csr,
    const float* __restrict__ b1, uint* __restrict__ x2, int n) {
    int wid = (blockIdx.x * 256 + threadIdx.x) >> 6;
    if (wid >= n) return;
    uint lane = threadIdx.x & 63;
    uint c0 = lane * 2;
    uint hd = lane >> 3;
    int beg = rowptr[wid], end = rowptr[wid + 1];
    float s = 0.f, acc0 = 0.f, acc1 = 0.f;
    for (int base = beg; base < end; base += 64) {
        int cnt = min(64, end - base);
        int vidx = ((int)lane < cnt) ? csr[base + lane] : 0;
        const _Float16* pp = p1 + (size_t)base * 8 + hd;
        int j = 0;
        for (; j + 8 <= cnt; j += 8) {
            uint s0 = __builtin_amdgcn_readlane(vidx, j);
            uint s1 = __builtin_amdgcn_readlane(vidx, j + 1);
            uint s2 = __builtin_amdgcn_readlane(vidx, j + 2);
            uint s3 = __builtin_amdgcn_readlane(vidx, j + 3);
            uint s4 = __builtin_amdgcn_readlane(vidx, j + 4);
            uint s5 = __builtin_amdgcn_readlane(vidx, j + 5);
            uint s6 = __builtin_amdgcn_readlane(vidx, j + 6);
            uint s7 = __builtin_amdgcn_readlane(vidx, j + 7);
            uint u0 = hu[s0 * 64u + lane];
            uint u1 = hu[s1 * 64u + lane];
            uint u2 = hu[s2 * 64u + lane];
            uint u3 = hu[s3 * 64u + lane];
            uint u4 = hu[s4 * 64u + lane];
            uint u5 = hu[s5 * 64u + lane];
            uint u6 = hu[s6 * 64u + lane];
            uint u7 = hu[s7 * 64u + lane];
            float q0 = (float)pp[(j + 0) * 8];
            float q1 = (float)pp[(j + 1) * 8];
            float q2 = (float)pp[(j + 2) * 8];
            float q3 = (float)pp[(j + 3) * 8];
            float q4 = (float)pp[(j + 4) * 8];
            float q5 = (float)pp[(j + 5) * 8];
            float q6 = (float)pp[(j + 6) * 8];
            float q7 = (float)pp[(j + 7) * 8];
            s += ((q0 + q1) + (q2 + q3)) + ((q4 + q5) + (q6 + q7));
            acc0 = fmaf(q0, bflo(u0), fmaf(q1, bflo(u1), acc0));
            acc0 = fmaf(q2, bflo(u2), fmaf(q3, bflo(u3), acc0));
            acc0 = fmaf(q4, bflo(u4), fmaf(q5, bflo(u5), acc0));
            acc0 = fmaf(q6, bflo(u6), fmaf(q7, bflo(u7), acc0));
            acc1 = fmaf(q0, bfhi(u0), fmaf(q1, bfhi(u1), acc1));
            acc1 = fmaf(q2, bfhi(u2), fmaf(q3, bfhi(u3), acc1));
            acc1 = fmaf(q4, bfhi(u4), fmaf(q5, bfhi(u5), acc1));
            acc1 = fmaf(q6, bfhi(u6), fmaf(q7, bfhi(u7), acc1));
        }
        for (; j < cnt; ++j) {
            uint s0 = __builtin_amdgcn_readlane(vidx, j);
            float q0 = (float)pp[j * 8];
            uint u0 = hu[s0 * 64u + lane];
            s += q0;
            acc0 = fmaf(q0, bflo(u0), acc0);
            acc1 = fmaf(q0, bfhi(u0), acc1);
        }
    }
    float inv = 1.f / (s + 1e-16f);
    float o0 = acc0 * inv + b1[c0];
    float o1 = acc1 * inv + b1[c0 + 1];
    o0 = o0 > 0.f ? o0 : (__expf(o0) - 1.f);  // ELU
    o1 = o1 > 0.f ? o1 : (__expf(o1) - 1.f);
    union { ushort b[2]; uint u; } pk;
    pk.b[0] = f2bf(o0);
    pk.b[1] = f2bf(o1);
    x2[(uint)wid * 64u + lane] = pk.u;
}

// conv2: p kept in REGISTER (lane computes its own slot's p), broadcast via
// readlane — no LDS, no barrier; gathers overlap the p chain freely.
__global__ __launch_bounds__(256) void k_agg2(
    const ushort* __restrict__ hb, const float* __restrict__ asrc,
    const float* __restrict__ adst, const int* __restrict__ rowptr,
    const int* __restrict__ csr, const float* __restrict__ b2,
    float* __restrict__ out, int n) {
    int wid = (blockIdx.x * 256 + threadIdx.x) >> 6;
    if (wid >= n) return;
    uint lane = threadIdx.x & 63;
    float adn = adst[wid];
    int beg = rowptr[wid], end = rowptr[wid + 1];
    float s = 0.f, acc = 0.f;
    for (int base = beg; base < end; base += 64) {
        int cnt = min(64, end - base);
        int vidx = csr[base + min((int)lane, cnt - 1)];
        float e = asrc[vidx] + adn;
        e = fmaxf(e, 0.2f * e);
        int pvi = __float_as_int(((int)lane < cnt) ? exp2f(e) : 0.f);
        int j = 0;
        for (; j + 8 <= cnt; j += 8) {
            uint s0 = __builtin_amdgcn_readlane(vidx, j);
            uint s1 = __builtin_amdgcn_readlane(vidx, j + 1);
            uint s2 = __builtin_amdgcn_readlane(vidx, j + 2);
            uint s3 = __builtin_amdgcn_readlane(vidx, j + 3);
            uint s4 = __builtin_amdgcn_readlane(vidx, j + 4);
            uint s5 = __builtin_amdgcn_readlane(vidx, j + 5);
            uint s6 = __builtin_amdgcn_readlane(vidx, j + 6);
            uint s7 = __builtin_amdgcn_readlane(vidx, j + 7);
            float h0 = bf1(hb[s0 * 64u + lane]);
            float h1 = bf1(hb[s1 * 64u + lane]);
            float h2 = bf1(hb[s2 * 64u + lane]);
            float h3 = bf1(hb[s3 * 64u + lane]);
            float h4 = bf1(hb[s4 * 64u + lane]);
            float h5 = bf1(hb[s5 * 64u + lane]);
            float h6 = bf1(hb[s6 * 64u + lane]);
            float h7 = bf1(hb[s7 * 64u + lane]);
            float q0 = __int_as_float(__builtin_amdgcn_readlane(pvi, j));
            float q1 = __int_as_float(__builtin_amdgcn_readlane(pvi, j + 1));
            float q2 = __int_as_float(__builtin_amdgcn_readlane(pvi, j + 2));
            float q3 = __int_as_float(__builtin_amdgcn_readlane(pvi, j + 3));
            float q4 = __int_as_float(__builtin_amdgcn_readlane(pvi, j + 4));
            float q5 = __int_as_float(__builtin_amdgcn_readlane(pvi, j + 5));
            float q6 = __int_as_float(__builtin_amdgcn_readlane(pvi, j + 6));
            float q7 = __int_as_float(__builtin_amdgcn_readlane(pvi, j + 7));
            s += ((q0 + q1) + (q2 + q3)) + ((q4 + q5) + (q6 + q7));
            acc = fmaf(q0, h0, fmaf(q1, h1, acc));
            acc = fmaf(q2, h2, fmaf(q3, h3, acc));
            acc = fmaf(q4, h4, fmaf(q5, h5, acc));
            acc = fmaf(q6, h6, fmaf(q7, h7, acc));
        }
        for (; j < cnt; ++j) {
            uint s0 = __builtin_amdgcn_readlane(vidx, j);
            float q0 = __int_as_float(__builtin_amdgcn_readlane(pvi, j));
            float h0 = bf1(hb[s0 * 64u + lane]);
            s += q0;
            acc = fmaf(q0, h0, acc);
        }
    }
    out[(size_t)wid * 64 + lane] = acc / (s + 1e-16f) + b2[lane];
}

// ------------------------------- launch -------------------------------------
extern "C" void kernel_launch(void* const* d_in, const int* in_sizes, int n_in,
                              void* d_out, int out_size, void* d_ws, size_t ws_size,
                              hipStream_t stream) {
    const float* x   = (const float*)d_in[0];
    const int*   ei  = (const int*)d_in[1];
    const float* W1  = (const float*)d_in[2];
    const float* as1 = (const float*)d_in[3];
    const float* ad1 = (const float*)d_in[4];
    const float* b1  = (const float*)d_in[5];
    const float* W2  = (const float*)d_in[6];
    const float* as2 = (const float*)d_in[7];
    const float* ad2 = (const float*)d_in[8];
    const float* b2  = (const float*)d_in[9];
    float* out = (float*)d_out;

    int N = in_sizes[0] / 128;
    int E = in_sizes[1] / 2;
    int TOT = E + N;
    const int* src = ei;
    const int* dst = ei + E;

    char* p = (char*)d_ws;
    auto alloc = [&](size_t bytes) {
        char* r = p;
        p += (bytes + 255) & ~size_t(255);
        return r;
    };
    ushort* h1b  = (ushort*)alloc((size_t)N * 128 * 2);
    ushort* h2b  = (ushort*)alloc((size_t)N * 64 * 2);
    ushort* x2b  = (ushort*)alloc((size_t)N * 128 * 2);
    _Float16* asrc1 = (_Float16*)alloc((size_t)N * 8 * 2);
    _Float16* adst1 = (_Float16*)alloc((size_t)N * 8 * 2);
    float* asrc2 = (float*)alloc((size_t)N * 4);
    float* adst2 = (float*)alloc((size_t)N * 4);
    int* rowptr  = (int*)alloc((size_t)(N + 1) * 4);
    int* csr     = (int*)alloc((size_t)TOT * 4);
    int* ebuf    = (int*)alloc((size_t)E * 4);
    _Float16* p1 = (_Float16*)alloc(((size_t)TOT * 8 + 16) * 2);
    int* bcount  = (int*)alloc(1024 * 4);
    int* ebase   = (int*)alloc(1024 * 4);
    int* ecur    = (int*)alloc(1024 * 4);
    int* cbase   = (int*)alloc(1024 * 4);

    int NB = (N + 127) >> 7;
    int nbp = (E + 8191) / 8192;
    int gb = (N + 127) / 128;

    hipMemsetAsync(bcount, 0, 1024 * 4, stream);
    k_gemm1_bhist<<<nbp + gb, 256, 0, stream>>>(x, W1, h1b, N, dst, E, bcount, nbp);
    k_bscan_attn1<<<1 + (N * 8 + 255) / 256, 256, 0, stream>>>(
        bcount, NB, N, ebase, ecur, cbase, (const uint*)h1b, as1, ad1, asrc1, adst1);
    k_part<<<nbp, 512, 0, stream>>>(src, dst, E, ecur, ebuf);
    k_build<<<NB, 256, 0, stream>>>(ebuf, bcount, ebase, cbase, asrc1, adst1,
                                    rowptr, csr, p1, N, NB);
    k_agg1<<<(N + 3) / 4, 256, 0, stream>>>((const uint*)h1b, p1, rowptr, csr, b1,
                                            (uint*)x2b, N);
    k_gemm2_attn2<<<gb, 256, 0, stream>>>(x2b, W2, h2b, as2, ad2, asrc2, adst2, N);
    k_agg2<<<(N + 3) / 4, 256, 0, stream>>>((const ushort*)h2b, asrc2, adst2, rowptr, csr, b2,
                                            out, N);
}